// Round 2
// 197.813 us; speedup vs baseline: 1.0718x; 1.0718x over previous
//
#include <hip/hip_runtime.h>
#include <math.h>

// NeRF ray integration, v6 (resubmit — round 1 failure was container infra,
// not the kernel). Single fused kernel.
//  - Color staged through LDS: block-coalesced global reads (3x dwordx4 per
//    thread, contiguous 12KB/block) replace the per-lane stride-48B color
//    loads that v5 issued (theory: 3x request count pinned K1 at ~3.4 TB/s).
//  - t-copy fused: tv is already in registers, store it to out_t directly.
//    Kills K2 and its 33MB t re-read.
//  - Same compute core: 2 rays/wave (32-lane segments), 4 samples/lane,
//    shfl_up inclusive scan for cumulative optical depth, 5 exp, shfl_xor
//    reductions for RGB+depth.

#define NRAYS 65536
#define S 128
#define RAYS_PER_BLOCK 8   // 4 waves * 2 rays

typedef float __attribute__((ext_vector_type(4))) fvec4;

__global__ __launch_bounds__(256) void nerf_fused_kernel(
    const float* __restrict__ t,
    const float* __restrict__ sigma,
    const float* __restrict__ color,
    float* __restrict__ out_color,   // [N,3]
    float* __restrict__ out_depth,   // [N,1]
    float* __restrict__ out_wi,      // [N,S]
    float* __restrict__ out_t)       // [N,S]
{
    // 8 rays * 128 samples * 3 ch = 3072 floats = 768 float4 = 12 KB
    __shared__ fvec4 lds_c[RAYS_PER_BLOCK * S * 3 / 4];

    const int tid     = threadIdx.x;
    const int lane    = tid & 63;
    const int seglane = lane & 31;
    const int seg     = tid >> 5;               // ray within block, 0..7
    const int ray     = blockIdx.x * RAYS_PER_BLOCK + seg;

    const long sbase = (long)ray * S + 4 * seglane;

    // ---- issue all global loads up front ----
    // coalesced color stage: block reads its contiguous 12KB span
    const fvec4* gc = (const fvec4*)(color + (long)blockIdx.x * (RAYS_PER_BLOCK * S * 3));
    const fvec4 g0 = __builtin_nontemporal_load(gc + tid);
    const fvec4 g1 = __builtin_nontemporal_load(gc + tid + 256);
    const fvec4 g2 = __builtin_nontemporal_load(gc + tid + 512);

    const fvec4 tv = __builtin_nontemporal_load((const fvec4*)(t + sbase));
    const fvec4 sv = __builtin_nontemporal_load((const fvec4*)(sigma + sbase));

    // fused t-copy (K2 is gone): tv is already here, store it out
    __builtin_nontemporal_store(tv, (fvec4*)(out_t + sbase));

    lds_c[tid]       = g0;
    lds_c[tid + 256] = g1;
    lds_c[tid + 512] = g2;
    __syncthreads();

    // per-lane color fragment: ray seg, samples 4*seglane..4*seglane+3
    // -> float4 indices seg*96 + 3*seglane + {0,1,2} (48B stride in LDS,
    //    ~4-way bank aliasing on ds_read_b128 — 1.58x on a ~12cy op, noise)
    const int cidx = seg * (S * 3 / 4) + 3 * seglane;
    const fvec4 c0 = lds_c[cidx + 0];
    const fvec4 c1 = lds_c[cidx + 1];
    const fvec4 c2 = lds_c[cidx + 2];

    // ---- dt ----
    const float t_next = __shfl_down(tv.x, 1, 32);
    const float dt0 = tv.y - tv.x;
    const float dt1 = tv.z - tv.y;
    const float dt2 = tv.w - tv.z;
    const float dt3 = (seglane == 31) ? 0.0f : (t_next - tv.w);

    // ---- per-lane prefix of sigma*dt ----
    const float p0  = sv.x * dt0;
    const float p1  = p0 + sv.y * dt1;
    const float p2  = p1 + sv.z * dt2;
    const float tot = p2 + sv.w * dt3;

    // ---- 32-lane inclusive scan of per-lane totals ----
    float scan = tot;
    #pragma unroll
    for (int off = 1; off < 32; off <<= 1) {
        const float v = __shfl_up(scan, off, 32);
        if (seglane >= off) scan += v;
    }
    const float excl = scan - tot;

    // ---- transmittance & weights ----
    const float E0 = __expf(-excl);
    const float e0 = __expf(-(excl + p0));
    const float e1 = __expf(-(excl + p1));
    const float e2 = __expf(-(excl + p2));
    const float e3 = __expf(-scan);
    const float wi0 = E0 - e0;
    const float wi1 = e0 - e1;
    const float wi2 = e1 - e2;
    const float wi3 = e2 - e3;

    fvec4 wiv; wiv.x = wi0; wiv.y = wi1; wiv.z = wi2; wiv.w = wi3;
    __builtin_nontemporal_store(wiv, (fvec4*)(out_wi + sbase));

    // ---- weighted color + depth ----
    // sample 4l+0: floats 12l+0..2  -> c0.x c0.y c0.z
    // sample 4l+1: floats 12l+3..5  -> c0.w c1.x c1.y
    // sample 4l+2: floats 12l+6..8  -> c1.z c1.w c2.x
    // sample 4l+3: floats 12l+9..11 -> c2.y c2.z c2.w
    float r = wi0 * c0.x + wi1 * c0.w + wi2 * c1.z + wi3 * c2.y;
    float g = wi0 * c0.y + wi1 * c1.x + wi2 * c1.w + wi3 * c2.z;
    float b = wi0 * c0.z + wi1 * c1.y + wi2 * c2.x + wi3 * c2.w;
    float d = wi0 * tv.x + wi1 * tv.y + wi2 * tv.z + wi3 * tv.w;

    #pragma unroll
    for (int off = 16; off >= 1; off >>= 1) {
        r += __shfl_xor(r, off, 32);
        g += __shfl_xor(g, off, 32);
        b += __shfl_xor(b, off, 32);
        d += __shfl_xor(d, off, 32);
    }

    if (seglane == 0) {
        out_color[(long)ray * 3 + 0] = r;
        out_color[(long)ray * 3 + 1] = g;
        out_color[(long)ray * 3 + 2] = b;
        out_depth[ray] = d;
    }
}

extern "C" void kernel_launch(void* const* d_in, const int* in_sizes, int n_in,
                              void* d_out, int out_size, void* d_ws, size_t ws_size,
                              hipStream_t stream) {
    const float* t     = (const float*)d_in[0];
    const float* sigma = (const float*)d_in[1];
    const float* color = (const float*)d_in[2];

    float* out = (float*)d_out;
    float* out_color = out;                         // N*3
    float* out_depth = out_color + (long)NRAYS * 3; // N
    float* out_wi    = out_depth + NRAYS;           // N*S
    float* out_t     = out_wi + (long)NRAYS * S;    // N*S

    const int blocks = NRAYS / RAYS_PER_BLOCK;      // 8192
    nerf_fused_kernel<<<blocks, 256, 0, stream>>>(
        t, sigma, color, out_color, out_depth, out_wi, out_t);
}